// Round 19
// baseline (125.373 us; speedup 1.0000x reference)
//
#include <hip/hip_runtime.h>

#define BATCH 8
#define NNODE 10000
#define NEDGE 320000
#define HD    128
#define NROW  (BATCH * NNODE)       // 80000 rows
#define NEDG_TOT (BATCH * NEDGE)    // 2.56M edges
#define LDW 136                     // padded LDS row stride (bf16)
#define KB  64                      // hist/scatter blocks per batch
#define CEB (NEDGE / KB)            // 5000 edges per block
#define G   64                      // rows per coarse bucket
#define NBUCK 157                   // ceil(NNODE/G)
#define NBP 160                     // padded bucket stride
#define NBT (BATCH * NBP)           // 1280
#define WCVT_B 192                  // 3*16384/256

typedef __attribute__((ext_vector_type(8))) short short8;
typedef __attribute__((ext_vector_type(4))) float f32x4;

__device__ __forceinline__ short f2bf(float f) {
    unsigned u = __float_as_uint(f);
    unsigned r = u + 0x7FFFu + ((u >> 16) & 1u);   // RNE
    return (short)(r >> 16);
}
__device__ __forceinline__ float bflo(unsigned y) { return __uint_as_float(y << 16); }
__device__ __forceinline__ float bfhi(unsigned y) { return __uint_as_float(y & 0xffff0000u); }

// ---------- pass 1: per-block coarse bucket counts (640B LDS, unroll 4) ----------
__global__ __launch_bounds__(512) void k_hist(const int* __restrict__ src,
                                              int* __restrict__ cc) {
    __shared__ int scc[NBP];
    int t = threadIdx.x, blk = blockIdx.x;
    if (t < NBP) scc[t] = 0;
    __syncthreads();
    int b = blk >> 6, kb = blk & (KB - 1);
    long e0 = (long)b * NEDGE + (long)kb * CEB;
    for (int i0 = t; i0 < CEB; i0 += 2048) {
        int i1 = i0 + 512, i2 = i0 + 1024, i3 = i0 + 1536;
        int s0 = src[e0 + i0];
        int s1 = (i1 < CEB) ? src[e0 + i1] : -1;
        int s2 = (i2 < CEB) ? src[e0 + i2] : -1;
        int s3 = (i3 < CEB) ? src[e0 + i3] : -1;
        atomicAdd(&scc[s0 >> 6], 1);
        if (s1 >= 0) atomicAdd(&scc[s1 >> 6], 1);
        if (s2 >= 0) atomicAdd(&scc[s2 >> 6], 1);
        if (s3 >= 0) atomicAdd(&scc[s3 >> 6], 1);
    }
    __syncthreads();
    if (t < NBP) cc[blk * NBP + t] = scc[t];
}

// ---------- wcvt (blocks 0..191) | parallel bucket totals (blocks 192..196) ----------
__global__ __launch_bounds__(256) void k_wsum(const float* __restrict__ th,
                                              const float* __restrict__ Wt,
                                              const float* __restrict__ Wh,
                                              short* __restrict__ wbf,
                                              const int* __restrict__ cc,
                                              int* __restrict__ tot_c) {
    int t = threadIdx.x, blk = blockIdx.x;
    if (blk < WCVT_B) {
        int i = blk * 256 + t;
        int w = i >> 14, idx = i & 16383;
        int n = idx >> 7, k = idx & 127;
        const float* W = (w == 0) ? th : ((w == 1) ? Wt : Wh);
        wbf[i] = f2bf(W[k * HD + n]);
    } else {
        int gi = (blk - WCVT_B) * 256 + t;     // 0..1279
        if (gi >= NBT) return;
        int b = gi / NBP, bk = gi % NBP;
        int s = 0;
        #pragma unroll
        for (int k = 0; k < KB; ++k) s += cc[(b * KB + k) * NBP + bk];
        tot_c[gi] = s;
    }
}

// ---------- single-block scan of 1280 pre-summed totals -> cbaseA / cbaseB ----------
__global__ __launch_bounds__(256) void k_scanc(const int* __restrict__ tot_c,
                                               int* __restrict__ cbaseA,
                                               int* __restrict__ cbaseB) {
    __shared__ int partA[256], partB[256];
    int t = threadIdx.x;
    int locA[5], locB[5]; int runA = 0, runB = 0;
    #pragma unroll
    for (int j = 0; j < 5; ++j) {
        int v = tot_c[t * 5 + j];
        locA[j] = runA; runA += v;
        locB[j] = runB; runB += (v + 3 * G + 3) & ~3;   // 4-aligned padded bound
    }
    partA[t] = runA; partB[t] = runB; __syncthreads();
    for (int off = 1; off < 256; off <<= 1) {
        int a = partA[t], bb = partB[t];
        int aa = (t >= off) ? partA[t - off] : 0;
        int ab = (t >= off) ? partB[t - off] : 0;
        __syncthreads();
        partA[t] = a + aa; partB[t] = bb + ab;
        __syncthreads();
    }
    int exA = (t == 0) ? 0 : partA[t - 1];
    int exB = (t == 0) ? 0 : partB[t - 1];
    #pragma unroll
    for (int j = 0; j < 5; ++j) {
        cbaseA[t * 5 + j] = exA + locA[j];
        cbaseB[t * 5 + j] = exB + locB[j];
    }
}

// ---------- parallel per-(block,bucket) base rewrite ----------
__global__ __launch_bounds__(256) void k_boffc(const int* __restrict__ cbaseA,
                                               int* __restrict__ cc) {
    int gi = blockIdx.x * 256 + threadIdx.x;
    if (gi >= NBT) return;
    int b = gi / NBP, bk = gi % NBP;
    int c[KB];
    #pragma unroll
    for (int k = 0; k < KB; ++k) c[k] = cc[(b * KB + k) * NBP + bk];
    int run = cbaseA[gi];
    #pragma unroll
    for (int k = 0; k < KB; ++k) {
        cc[(b * KB + k) * NBP + bk] = run;
        run += c[k];
    }
}

// ---------- coarse scatter: 512 threads, unroll 4, KB=64 -> 2 blocks/CU ----------
__global__ __launch_bounds__(512) void k_scatA(const float* __restrict__ adj,
                                               const int* __restrict__ src,
                                               const int* __restrict__ dst,
                                               const int* __restrict__ cbases,
                                               int2* __restrict__ epairA) {
    __shared__ int cur[NBP];
    int t = threadIdx.x, blk = blockIdx.x;
    if (t < NBP) cur[t] = cbases[blk * NBP + t];
    __syncthreads();
    int b = blk >> 6, kb = blk & (KB - 1);
    long e0 = (long)b * NEDGE + (long)kb * CEB;
    for (int i0 = t; i0 < CEB; i0 += 2048) {
        int i1 = i0 + 512, i2 = i0 + 1024, i3 = i0 + 1536;
        int s0 = src[e0 + i0], d0 = dst[e0 + i0];
        float a0 = adj[e0 + i0];
        int s1 = -1, d1 = 0; float a1 = 0.f;
        int s2 = -1, d2 = 0; float a2 = 0.f;
        int s3 = -1, d3 = 0; float a3 = 0.f;
        if (i1 < CEB) { s1 = src[e0 + i1]; d1 = dst[e0 + i1]; a1 = adj[e0 + i1]; }
        if (i2 < CEB) { s2 = src[e0 + i2]; d2 = dst[e0 + i2]; a2 = adj[e0 + i2]; }
        if (i3 < CEB) { s3 = src[e0 + i3]; d3 = dst[e0 + i3]; a3 = adj[e0 + i3]; }
        int p0 = atomicAdd(&cur[s0 >> 6], 1);
        epairA[p0] = make_int2((s0 << 16) | d0, __float_as_int(a0));
        if (s1 >= 0) {
            int p1 = atomicAdd(&cur[s1 >> 6], 1);
            epairA[p1] = make_int2((s1 << 16) | d1, __float_as_int(a1));
        }
        if (s2 >= 0) {
            int p2 = atomicAdd(&cur[s2 >> 6], 1);
            epairA[p2] = make_int2((s2 << 16) | d2, __float_as_int(a2));
        }
        if (s3 >= 0) {
            int p3 = atomicAdd(&cur[s3 >> 6], 1);
            epairA[p3] = make_int2((s3 << 16) | d3, __float_as_int(a3));
        }
    }
}

// ---------- refine: row counts + degree -> norm, rowptr/total, packed 4B edges ----------
__global__ __launch_bounds__(256) void k_refine(const int* __restrict__ cbaseA,
                                                const int* __restrict__ cbaseB,
                                                const int* __restrict__ tot_c,
                                                const int2* __restrict__ epairA,
                                                int* __restrict__ rowptr,
                                                int* __restrict__ total,
                                                float* __restrict__ norm,
                                                int* __restrict__ epakB) {
    __shared__ int   rcnt[G];
    __shared__ float sdeg[G];
    __shared__ int   rcur[G];
    int t = threadIdx.x;
    int batch = blockIdx.x & 7, bk = blockIdx.x >> 3;
    if (t < G) { rcnt[t] = 0; sdeg[t] = 0.f; }
    __syncthreads();
    int gi = batch * NBP + bk;
    int p0 = cbaseA[gi], n = tot_c[gi], pB = cbaseB[gi];
    for (int i = t; i < n; i += 256) {
        int2 e = epairA[p0 + i];
        int rl = (e.x >> 16) & (G - 1);
        atomicAdd(&rcnt[rl], 1);
        atomicAdd(&sdeg[rl], __int_as_float(e.y));
    }
    __syncthreads();
    if (t < G) {
        int v = rcnt[t];
        int pv = (v + 3) & ~3;
        int inc = pv;
        #pragma unroll
        for (int off = 1; off < G; off <<= 1) {
            int u = __shfl_up(inc, off, G);
            if (t >= off) inc += u;
        }
        int start = pB + inc - pv;
        rcur[t] = start;
        int node = bk * G + t;
        if (node < NNODE) {
            long r = (long)batch * NNODE + node;
            rowptr[r] = start;
            total[r] = v;
            norm[r] = rsqrtf(sdeg[t] + 1e-6f);
        }
    }
    __syncthreads();
    for (int i = t; i < n; i += 256) {
        int2 e = epairA[p0 + i];
        int rl = (e.x >> 16) & (G - 1);
        int p = atomicAdd(&rcur[rl], 1);
        unsigned vbf = (unsigned short)f2bf(__int_as_float(e.y));
        epakB[p] = (e.x & 0xffff) | (vbf << 16);
    }
}

// ---------- fused 3-GEMM, single LDS slot (34.8KB -> 4 blocks/CU), 3 passes ----------
__global__ __launch_bounds__(256) void k_gemm3(const float* __restrict__ x,
                                               const short* __restrict__ wbf,  // thT|WtT|WhT
                                               const float* __restrict__ norm,
                                               const float* __restrict__ bt,
                                               short* __restrict__ Y,
                                               unsigned* __restrict__ outgh) {
    __shared__ short lb[HD * LDW];       // 34816 B -> 4 blocks/CU
    int tx = threadIdx.x;
    int wv = tx >> 6, l = tx & 63;
    long row0 = (long)blockIdx.x * 64 + wv * 16;
    int mrow = l & 15, kg = l >> 4;
    const float* xp = x + (row0 + mrow) * HD + kg * 8;

    short8 af[4];
    #pragma unroll
    for (int c = 0; c < 4; ++c) {
        float4 a0 = *(const float4*)(xp + c * 32);
        float4 a1 = *(const float4*)(xp + c * 32 + 4);
        short8 a;
        a[0]=f2bf(a0.x); a[1]=f2bf(a0.y); a[2]=f2bf(a0.z); a[3]=f2bf(a0.w);
        a[4]=f2bf(a1.x); a[5]=f2bf(a1.y); a[6]=f2bf(a1.z); a[7]=f2bf(a1.w);
        af[c] = a;
    }

    // ---- pass 1: theta ----
    for (int i = tx; i < HD * 16; i += 256) {
        int n = i >> 4, kc = (i & 15) << 3;
        *(float4*)(&lb[n * LDW + kc]) = *(const float4*)(&wbf[n * HD + kc]);
    }
    __syncthreads();
    f32x4 ac[8];
    #pragma unroll
    for (int f = 0; f < 8; ++f) ac[f] = (f32x4){0.f,0.f,0.f,0.f};
    #pragma unroll
    for (int c = 0; c < 4; ++c)
        #pragma unroll
        for (int f = 0; f < 8; ++f) {
            short8 b = *(short8*)(&lb[(16 * f + mrow) * LDW + c * 32 + kg * 8]);
            ac[f] = __builtin_amdgcn_mfma_f32_16x16x32_bf16(af[c], b, ac[f], 0, 0, 0);
        }
    float nr[4];
    #pragma unroll
    for (int r = 0; r < 4; ++r) nr[r] = norm[row0 + kg * 4 + r];
    #pragma unroll
    for (int f = 0; f < 8; ++f)
        #pragma unroll
        for (int r = 0; r < 4; ++r)
            Y[(row0 + kg * 4 + r) * HD + 16 * f + mrow] = f2bf(ac[f][r] * nr[r]);

    // ---- pass 2: W_t -> gate ----
    __syncthreads();
    for (int i = tx; i < HD * 16; i += 256) {
        int n = i >> 4, kc = (i & 15) << 3;
        *(float4*)(&lb[n * LDW + kc]) = *(const float4*)(&wbf[16384 + n * HD + kc]);
    }
    __syncthreads();
    #pragma unroll
    for (int f = 0; f < 8; ++f) ac[f] = (f32x4){0.f,0.f,0.f,0.f};
    #pragma unroll
    for (int c = 0; c < 4; ++c)
        #pragma unroll
        for (int f = 0; f < 8; ++f) {
            short8 b = *(short8*)(&lb[(16 * f + mrow) * LDW + c * 32 + kg * 8]);
            ac[f] = __builtin_amdgcn_mfma_f32_16x16x32_bf16(af[c], b, ac[f], 0, 0, 0);
        }
    unsigned g16[16];
    #pragma unroll
    for (int f = 0; f < 8; ++f) {
        float bb = bt[16 * f + mrow];
        #pragma unroll
        for (int r = 0; r < 4; ++r) {
            int q = f * 4 + r;
            float g = 1.f / (1.f + __expf(-(ac[f][r] + bb)));
            unsigned gb = (unsigned short)f2bf(g);
            if (q & 1) g16[q >> 1] |= gb << 16;
            else       g16[q >> 1]  = gb;
        }
    }

    // ---- pass 3: W_h -> het; pack gate|het into out ----
    __syncthreads();
    for (int i = tx; i < HD * 16; i += 256) {
        int n = i >> 4, kc = (i & 15) << 3;
        *(float4*)(&lb[n * LDW + kc]) = *(const float4*)(&wbf[2 * 16384 + n * HD + kc]);
    }
    __syncthreads();
    #pragma unroll
    for (int f = 0; f < 8; ++f) ac[f] = (f32x4){0.f,0.f,0.f,0.f};
    #pragma unroll
    for (int c = 0; c < 4; ++c)
        #pragma unroll
        for (int f = 0; f < 8; ++f) {
            short8 b = *(short8*)(&lb[(16 * f + mrow) * LDW + c * 32 + kg * 8]);
            ac[f] = __builtin_amdgcn_mfma_f32_16x16x32_bf16(af[c], b, ac[f], 0, 0, 0);
        }
    #pragma unroll
    for (int f = 0; f < 8; ++f)
        #pragma unroll
        for (int r = 0; r < 4; ++r) {
            int q = f * 4 + r;
            long idx = (row0 + kg * 4 + r) * HD + 16 * f + mrow;
            unsigned gb = (q & 1) ? (g16[q >> 1] >> 16) : (g16[q >> 1] & 0xffffu);
            unsigned hhi = (unsigned short)f2bf(ac[f][r]);
            outgh[idx] = gb | (hhi << 16);
        }
}

// ---------- gather: 2 rows/wave with INTERLEAVED edge loops (2 indep chains) ----------
__global__ __launch_bounds__(256) void k_gather(const int* __restrict__ rowptr,
                                                const int* __restrict__ total,
                                                const int* __restrict__ epak,
                                                const short* __restrict__ Y,
                                                const float* __restrict__ norm,
                                                float* __restrict__ out) {
    int batch = blockIdx.x & 7;
    int ib    = blockIdx.x >> 3;
    int wave = threadIdx.x >> 6, lane = threadIdx.x & 63;
    long r0 = (long)batch * NNODE + ib * 8 + wave * 2;
    long r1 = r0 + 1;
    uint2 gh0 = ((const uint2*)(out + r0 * HD))[lane];
    uint2 gh1 = ((const uint2*)(out + r1 * HD))[lane];
    float nrm0 = norm[r0], nrm1 = norm[r1];
    int p0a = __builtin_amdgcn_readfirstlane(rowptr[r0]);
    int n0  = __builtin_amdgcn_readfirstlane(total[r0]);
    int p1a = __builtin_amdgcn_readfirstlane(rowptr[r1]);
    int n1  = __builtin_amdgcn_readfirstlane(total[r1]);
    const char* Yb = (const char*)Y + (size_t)batch * NNODE * HD * 2;  // scalar base
    unsigned lo4 = (unsigned)lane * 4;
    const int* ep0 = epak + p0a;
    const int* ep1 = epak + p1a;

    float ax0 = 0.f, ay0 = 0.f, ax1 = 0.f, ay1 = 0.f;
    int i0 = 0, i1 = 0;

    // interleaved 8-edge groups: both rows' meta+Y loads in flight together
    while ((i0 + 8 <= n0) | (i1 + 8 <= n1)) {
        bool d0 = (i0 + 8 <= n0);
        bool d1 = (i1 + 8 <= n1);
        int4 mA0, mB0, mA1, mB1;
        if (d0) { mA0 = *(const int4*)(ep0 + i0); mB0 = *(const int4*)(ep0 + i0 + 4); }
        if (d1) { mA1 = *(const int4*)(ep1 + i1); mB1 = *(const int4*)(ep1 + i1 + 4); }
        unsigned p0[8], p1[8];
        if (d0) {
            p0[0] = *(const unsigned*)(Yb + (((unsigned)mA0.x & 0xffffu) << 8) + lo4);
            p0[1] = *(const unsigned*)(Yb + (((unsigned)mA0.y & 0xffffu) << 8) + lo4);
            p0[2] = *(const unsigned*)(Yb + (((unsigned)mA0.z & 0xffffu) << 8) + lo4);
            p0[3] = *(const unsigned*)(Yb + (((unsigned)mA0.w & 0xffffu) << 8) + lo4);
            p0[4] = *(const unsigned*)(Yb + (((unsigned)mB0.x & 0xffffu) << 8) + lo4);
            p0[5] = *(const unsigned*)(Yb + (((unsigned)mB0.y & 0xffffu) << 8) + lo4);
            p0[6] = *(const unsigned*)(Yb + (((unsigned)mB0.z & 0xffffu) << 8) + lo4);
            p0[7] = *(const unsigned*)(Yb + (((unsigned)mB0.w & 0xffffu) << 8) + lo4);
        }
        if (d1) {
            p1[0] = *(const unsigned*)(Yb + (((unsigned)mA1.x & 0xffffu) << 8) + lo4);
            p1[1] = *(const unsigned*)(Yb + (((unsigned)mA1.y & 0xffffu) << 8) + lo4);
            p1[2] = *(const unsigned*)(Yb + (((unsigned)mA1.z & 0xffffu) << 8) + lo4);
            p1[3] = *(const unsigned*)(Yb + (((unsigned)mA1.w & 0xffffu) << 8) + lo4);
            p1[4] = *(const unsigned*)(Yb + (((unsigned)mB1.x & 0xffffu) << 8) + lo4);
            p1[5] = *(const unsigned*)(Yb + (((unsigned)mB1.y & 0xffffu) << 8) + lo4);
            p1[6] = *(const unsigned*)(Yb + (((unsigned)mB1.z & 0xffffu) << 8) + lo4);
            p1[7] = *(const unsigned*)(Yb + (((unsigned)mB1.w & 0xffffu) << 8) + lo4);
        }
        if (d0) {
            float v0 = bfhi((unsigned)mA0.x), v1 = bfhi((unsigned)mA0.y);
            float v2 = bfhi((unsigned)mA0.z), v3 = bfhi((unsigned)mA0.w);
            float v4 = bfhi((unsigned)mB0.x), v5 = bfhi((unsigned)mB0.y);
            float v6 = bfhi((unsigned)mB0.z), v7 = bfhi((unsigned)mB0.w);
            ax0 += v0 * bflo(p0[0]); ay0 += v0 * bfhi(p0[0]);
            ax0 += v1 * bflo(p0[1]); ay0 += v1 * bfhi(p0[1]);
            ax0 += v2 * bflo(p0[2]); ay0 += v2 * bfhi(p0[2]);
            ax0 += v3 * bflo(p0[3]); ay0 += v3 * bfhi(p0[3]);
            ax0 += v4 * bflo(p0[4]); ay0 += v4 * bfhi(p0[4]);
            ax0 += v5 * bflo(p0[5]); ay0 += v5 * bfhi(p0[5]);
            ax0 += v6 * bflo(p0[6]); ay0 += v6 * bfhi(p0[6]);
            ax0 += v7 * bflo(p0[7]); ay0 += v7 * bfhi(p0[7]);
            i0 += 8;
        }
        if (d1) {
            float v0 = bfhi((unsigned)mA1.x), v1 = bfhi((unsigned)mA1.y);
            float v2 = bfhi((unsigned)mA1.z), v3 = bfhi((unsigned)mA1.w);
            float v4 = bfhi((unsigned)mB1.x), v5 = bfhi((unsigned)mB1.y);
            float v6 = bfhi((unsigned)mB1.z), v7 = bfhi((unsigned)mB1.w);
            ax1 += v0 * bflo(p1[0]); ay1 += v0 * bfhi(p1[0]);
            ax1 += v1 * bflo(p1[1]); ay1 += v1 * bfhi(p1[1]);
            ax1 += v2 * bflo(p1[2]); ay1 += v2 * bfhi(p1[2]);
            ax1 += v3 * bflo(p1[3]); ay1 += v3 * bfhi(p1[3]);
            ax1 += v4 * bflo(p1[4]); ay1 += v4 * bfhi(p1[4]);
            ax1 += v5 * bflo(p1[5]); ay1 += v5 * bfhi(p1[5]);
            ax1 += v6 * bflo(p1[6]); ay1 += v6 * bfhi(p1[6]);
            ax1 += v7 * bflo(p1[7]); ay1 += v7 * bfhi(p1[7]);
            i1 += 8;
        }
    }
    // tails (interleave the two rows' 4-groups too)
    {
        bool d0 = (i0 + 4 <= n0);
        bool d1 = (i1 + 4 <= n1);
        int4 mA0, mA1;
        if (d0) mA0 = *(const int4*)(ep0 + i0);
        if (d1) mA1 = *(const int4*)(ep1 + i1);
        if (d0) {
            unsigned y0 = *(const unsigned*)(Yb + (((unsigned)mA0.x & 0xffffu) << 8) + lo4);
            unsigned y1 = *(const unsigned*)(Yb + (((unsigned)mA0.y & 0xffffu) << 8) + lo4);
            unsigned y2 = *(const unsigned*)(Yb + (((unsigned)mA0.z & 0xffffu) << 8) + lo4);
            unsigned y3 = *(const unsigned*)(Yb + (((unsigned)mA0.w & 0xffffu) << 8) + lo4);
            float v0 = bfhi((unsigned)mA0.x), v1 = bfhi((unsigned)mA0.y);
            float v2 = bfhi((unsigned)mA0.z), v3 = bfhi((unsigned)mA0.w);
            ax0 += v0 * bflo(y0); ay0 += v0 * bfhi(y0);
            ax0 += v1 * bflo(y1); ay0 += v1 * bfhi(y1);
            ax0 += v2 * bflo(y2); ay0 += v2 * bfhi(y2);
            ax0 += v3 * bflo(y3); ay0 += v3 * bfhi(y3);
            i0 += 4;
        }
        if (d1) {
            unsigned y0 = *(const unsigned*)(Yb + (((unsigned)mA1.x & 0xffffu) << 8) + lo4);
            unsigned y1 = *(const unsigned*)(Yb + (((unsigned)mA1.y & 0xffffu) << 8) + lo4);
            unsigned y2 = *(const unsigned*)(Yb + (((unsigned)mA1.z & 0xffffu) << 8) + lo4);
            unsigned y3 = *(const unsigned*)(Yb + (((unsigned)mA1.w & 0xffffu) << 8) + lo4);
            float v0 = bfhi((unsigned)mA1.x), v1 = bfhi((unsigned)mA1.y);
            float v2 = bfhi((unsigned)mA1.z), v3 = bfhi((unsigned)mA1.w);
            ax1 += v0 * bflo(y0); ay1 += v0 * bfhi(y0);
            ax1 += v1 * bflo(y1); ay1 += v1 * bfhi(y1);
            ax1 += v2 * bflo(y2); ay1 += v2 * bfhi(y2);
            ax1 += v3 * bflo(y3); ay1 += v3 * bfhi(y3);
            i1 += 4;
        }
    }
    for (; i0 < n0; ++i0) {
        unsigned e = (unsigned)ep0[i0];
        unsigned y = *(const unsigned*)(Yb + ((e & 0xffffu) << 8) + lo4);
        float v = bfhi(e);
        ax0 += v * bflo(y); ay0 += v * bfhi(y);
    }
    for (; i1 < n1; ++i1) {
        unsigned e = (unsigned)ep1[i1];
        unsigned y = *(const unsigned*)(Yb + ((e & 0xffffu) << 8) + lo4);
        float v = bfhi(e);
        ax1 += v * bflo(y); ay1 += v * bfhi(y);
    }

    {
        float g0 = bflo(gh0.x), h0 = bfhi(gh0.x);
        float g1 = bflo(gh0.y), h1 = bfhi(gh0.y);
        float z0 = ax0 * nrm0, z1 = ay0 * nrm0;
        ((float2*)(out + r0 * HD))[lane] =
            make_float2(g0 * z0 + (1.f - g0) * h0, g1 * z1 + (1.f - g1) * h1);
    }
    {
        float g0 = bflo(gh1.x), h0 = bfhi(gh1.x);
        float g1 = bflo(gh1.y), h1 = bfhi(gh1.y);
        float z0 = ax1 * nrm1, z1 = ay1 * nrm1;
        ((float2*)(out + r1 * HD))[lane] =
            make_float2(g0 * z0 + (1.f - g0) * h0, g1 * z1 + (1.f - g1) * h1);
    }
}

extern "C" void kernel_launch(void* const* d_in, const int* in_sizes, int n_in,
                              void* d_out, int out_size, void* d_ws, size_t ws_size,
                              hipStream_t stream) {
    const float* x     = (const float*)d_in[0];
    const float* adj   = (const float*)d_in[1];
    const int*   src   = (const int*)d_in[2];
    const int*   dst   = (const int*)d_in[3];
    const float* Wt    = (const float*)d_in[4];
    const float* bt    = (const float*)d_in[5];
    const float* Wh    = (const float*)d_in[6];
    const float* theta = (const float*)d_in[7];
    float* out = (float*)d_out;

    // workspace ~33.5 MB
    char* p = (char*)d_ws;
    float* norm   = (float*)p;  p += (size_t)NROW * 4;              // 320,000
    int*   total  = (int*)p;    p += (size_t)NROW * 4;              // 320,000
    int*   rowptr = (int*)p;    p += (size_t)NROW * 4;              // 320,000
    int*   tot_c  = (int*)p;    p += (size_t)NBT * 4;               // 5,120
    int*   cbaseA = (int*)p;    p += (size_t)NBT * 4;               // 5,120
    int*   cbaseB = (int*)p;    p += (size_t)NBT * 4;               // 5,120
    int*   cc     = (int*)p;    p += (size_t)BATCH * KB * NBP * 4;  // 327,680
    short* wbf    = (short*)p;  p += 3 * 16384 * 2;                 // 98,304
    // RegionA (20.48 MB): epairA (20.48M) -> Y (20.48M, after refine)
    int2*  epairA = (int2*)p;
    short* Y      = (short*)p;  p += (size_t)NROW * HD * 2;         // 20,480,000
    // RegionB: packed 4B edges, 4-padded rows
    int*   epakB  = (int*)p;    p += (size_t)(NEDG_TOT + NBT * 256) * 4; // 11,551,232

    k_hist  <<<BATCH * KB, 512, 0, stream>>>(src, cc);
    k_wsum  <<<WCVT_B + NBT / 256, 256, 0, stream>>>(theta, Wt, Wh, wbf, cc, tot_c);
    k_scanc <<<1, 256, 0, stream>>>(tot_c, cbaseA, cbaseB);
    k_boffc <<<NBT / 256, 256, 0, stream>>>(cbaseA, cc);
    k_scatA <<<BATCH * KB, 512, 0, stream>>>(adj, src, dst, cc, epairA);
    k_refine<<<BATCH * NBUCK, 256, 0, stream>>>(cbaseA, cbaseB, tot_c, epairA,
                                                rowptr, total, norm, epakB);
    k_gemm3 <<<NROW / 64, 256, 0, stream>>>(x, wbf, norm, bt, Y, (unsigned*)out); // Y over dead epairA
    k_gather<<<NROW / 8, 256, 0, stream>>>(rowptr, total, epakB, Y, norm, out);
}

// Round 20
// 123.133 us; speedup vs baseline: 1.0182x; 1.0182x over previous
//
#include <hip/hip_runtime.h>

#define BATCH 8
#define NNODE 10000
#define NEDGE 320000
#define HD    128
#define NROW  (BATCH * NNODE)       // 80000 rows
#define NEDG_TOT (BATCH * NEDGE)    // 2.56M edges
#define LDW 136                     // padded LDS row stride (bf16)
#define KB  64                      // hist/scatter blocks per batch
#define CEB (NEDGE / KB)            // 5000 edges per block
#define G   64                      // rows per coarse bucket
#define NBUCK 157                   // ceil(NNODE/G)
#define NBP 160                     // padded bucket stride
#define NBT (BATCH * NBP)           // 1280
#define WCVT_B 192                  // 3*16384/256

typedef __attribute__((ext_vector_type(8))) short short8;
typedef __attribute__((ext_vector_type(4))) float f32x4;

__device__ __forceinline__ short f2bf(float f) {
    unsigned u = __float_as_uint(f);
    unsigned r = u + 0x7FFFu + ((u >> 16) & 1u);   // RNE
    return (short)(r >> 16);
}
__device__ __forceinline__ float bflo(unsigned y) { return __uint_as_float(y << 16); }
__device__ __forceinline__ float bfhi(unsigned y) { return __uint_as_float(y & 0xffff0000u); }

// ---------- pass 1: per-block coarse bucket counts (640B LDS, unroll 4) ----------
__global__ __launch_bounds__(512) void k_hist(const int* __restrict__ src,
                                              int* __restrict__ cc) {
    __shared__ int scc[NBP];
    int t = threadIdx.x, blk = blockIdx.x;
    if (t < NBP) scc[t] = 0;
    __syncthreads();
    int b = blk >> 6, kb = blk & (KB - 1);
    long e0 = (long)b * NEDGE + (long)kb * CEB;
    for (int i0 = t; i0 < CEB; i0 += 2048) {
        int i1 = i0 + 512, i2 = i0 + 1024, i3 = i0 + 1536;
        int s0 = src[e0 + i0];
        int s1 = (i1 < CEB) ? src[e0 + i1] : -1;
        int s2 = (i2 < CEB) ? src[e0 + i2] : -1;
        int s3 = (i3 < CEB) ? src[e0 + i3] : -1;
        atomicAdd(&scc[s0 >> 6], 1);
        if (s1 >= 0) atomicAdd(&scc[s1 >> 6], 1);
        if (s2 >= 0) atomicAdd(&scc[s2 >> 6], 1);
        if (s3 >= 0) atomicAdd(&scc[s3 >> 6], 1);
    }
    __syncthreads();
    if (t < NBP) cc[blk * NBP + t] = scc[t];
}

// ---------- wcvt (blocks 0..191) | parallel bucket totals (blocks 192..196) ----------
__global__ __launch_bounds__(256) void k_wsum(const float* __restrict__ th,
                                              const float* __restrict__ Wt,
                                              const float* __restrict__ Wh,
                                              short* __restrict__ wbf,
                                              const int* __restrict__ cc,
                                              int* __restrict__ tot_c) {
    int t = threadIdx.x, blk = blockIdx.x;
    if (blk < WCVT_B) {
        int i = blk * 256 + t;
        int w = i >> 14, idx = i & 16383;
        int n = idx >> 7, k = idx & 127;
        const float* W = (w == 0) ? th : ((w == 1) ? Wt : Wh);
        wbf[i] = f2bf(W[k * HD + n]);
    } else {
        int gi = (blk - WCVT_B) * 256 + t;     // 0..1279
        if (gi >= NBT) return;
        int b = gi / NBP, bk = gi % NBP;
        int s = 0;
        #pragma unroll
        for (int k = 0; k < KB; ++k) s += cc[(b * KB + k) * NBP + bk];
        tot_c[gi] = s;
    }
}

// ---------- single-block scan of 1280 pre-summed totals -> cbaseA / cbaseB ----------
__global__ __launch_bounds__(256) void k_scanc(const int* __restrict__ tot_c,
                                               int* __restrict__ cbaseA,
                                               int* __restrict__ cbaseB) {
    __shared__ int partA[256], partB[256];
    int t = threadIdx.x;
    int locA[5], locB[5]; int runA = 0, runB = 0;
    #pragma unroll
    for (int j = 0; j < 5; ++j) {
        int v = tot_c[t * 5 + j];
        locA[j] = runA; runA += v;
        locB[j] = runB; runB += (v + 3 * G + 3) & ~3;   // 4-aligned padded bound
    }
    partA[t] = runA; partB[t] = runB; __syncthreads();
    for (int off = 1; off < 256; off <<= 1) {
        int a = partA[t], bb = partB[t];
        int aa = (t >= off) ? partA[t - off] : 0;
        int ab = (t >= off) ? partB[t - off] : 0;
        __syncthreads();
        partA[t] = a + aa; partB[t] = bb + ab;
        __syncthreads();
    }
    int exA = (t == 0) ? 0 : partA[t - 1];
    int exB = (t == 0) ? 0 : partB[t - 1];
    #pragma unroll
    for (int j = 0; j < 5; ++j) {
        cbaseA[t * 5 + j] = exA + locA[j];
        cbaseB[t * 5 + j] = exB + locB[j];
    }
}

// ---------- parallel per-(block,bucket) base rewrite ----------
__global__ __launch_bounds__(256) void k_boffc(const int* __restrict__ cbaseA,
                                               int* __restrict__ cc) {
    int gi = blockIdx.x * 256 + threadIdx.x;
    if (gi >= NBT) return;
    int b = gi / NBP, bk = gi % NBP;
    int c[KB];
    #pragma unroll
    for (int k = 0; k < KB; ++k) c[k] = cc[(b * KB + k) * NBP + bk];
    int run = cbaseA[gi];
    #pragma unroll
    for (int k = 0; k < KB; ++k) {
        cc[(b * KB + k) * NBP + bk] = run;
        run += c[k];
    }
}

// ---------- coarse scatter: 512 threads, unroll 4, KB=64 -> 2 blocks/CU ----------
__global__ __launch_bounds__(512) void k_scatA(const float* __restrict__ adj,
                                               const int* __restrict__ src,
                                               const int* __restrict__ dst,
                                               const int* __restrict__ cbases,
                                               int2* __restrict__ epairA) {
    __shared__ int cur[NBP];
    int t = threadIdx.x, blk = blockIdx.x;
    if (t < NBP) cur[t] = cbases[blk * NBP + t];
    __syncthreads();
    int b = blk >> 6, kb = blk & (KB - 1);
    long e0 = (long)b * NEDGE + (long)kb * CEB;
    for (int i0 = t; i0 < CEB; i0 += 2048) {
        int i1 = i0 + 512, i2 = i0 + 1024, i3 = i0 + 1536;
        int s0 = src[e0 + i0], d0 = dst[e0 + i0];
        float a0 = adj[e0 + i0];
        int s1 = -1, d1 = 0; float a1 = 0.f;
        int s2 = -1, d2 = 0; float a2 = 0.f;
        int s3 = -1, d3 = 0; float a3 = 0.f;
        if (i1 < CEB) { s1 = src[e0 + i1]; d1 = dst[e0 + i1]; a1 = adj[e0 + i1]; }
        if (i2 < CEB) { s2 = src[e0 + i2]; d2 = dst[e0 + i2]; a2 = adj[e0 + i2]; }
        if (i3 < CEB) { s3 = src[e0 + i3]; d3 = dst[e0 + i3]; a3 = adj[e0 + i3]; }
        int p0 = atomicAdd(&cur[s0 >> 6], 1);
        epairA[p0] = make_int2((s0 << 16) | d0, __float_as_int(a0));
        if (s1 >= 0) {
            int p1 = atomicAdd(&cur[s1 >> 6], 1);
            epairA[p1] = make_int2((s1 << 16) | d1, __float_as_int(a1));
        }
        if (s2 >= 0) {
            int p2 = atomicAdd(&cur[s2 >> 6], 1);
            epairA[p2] = make_int2((s2 << 16) | d2, __float_as_int(a2));
        }
        if (s3 >= 0) {
            int p3 = atomicAdd(&cur[s3 >> 6], 1);
            epairA[p3] = make_int2((s3 << 16) | d3, __float_as_int(a3));
        }
    }
}

// ---------- refine: row counts + degree -> norm, rowptr/total, packed 4B edges ----------
__global__ __launch_bounds__(256) void k_refine(const int* __restrict__ cbaseA,
                                                const int* __restrict__ cbaseB,
                                                const int* __restrict__ tot_c,
                                                const int2* __restrict__ epairA,
                                                int* __restrict__ rowptr,
                                                int* __restrict__ total,
                                                float* __restrict__ norm,
                                                int* __restrict__ epakB) {
    __shared__ int   rcnt[G];
    __shared__ float sdeg[G];
    __shared__ int   rcur[G];
    int t = threadIdx.x;
    int batch = blockIdx.x & 7, bk = blockIdx.x >> 3;
    if (t < G) { rcnt[t] = 0; sdeg[t] = 0.f; }
    __syncthreads();
    int gi = batch * NBP + bk;
    int p0 = cbaseA[gi], n = tot_c[gi], pB = cbaseB[gi];
    for (int i = t; i < n; i += 256) {
        int2 e = epairA[p0 + i];
        int rl = (e.x >> 16) & (G - 1);
        atomicAdd(&rcnt[rl], 1);
        atomicAdd(&sdeg[rl], __int_as_float(e.y));
    }
    __syncthreads();
    if (t < G) {
        int v = rcnt[t];
        int pv = (v + 3) & ~3;
        int inc = pv;
        #pragma unroll
        for (int off = 1; off < G; off <<= 1) {
            int u = __shfl_up(inc, off, G);
            if (t >= off) inc += u;
        }
        int start = pB + inc - pv;
        rcur[t] = start;
        int node = bk * G + t;
        if (node < NNODE) {
            long r = (long)batch * NNODE + node;
            rowptr[r] = start;
            total[r] = v;
            norm[r] = rsqrtf(sdeg[t] + 1e-6f);
        }
    }
    __syncthreads();
    for (int i = t; i < n; i += 256) {
        int2 e = epairA[p0 + i];
        int rl = (e.x >> 16) & (G - 1);
        int p = atomicAdd(&rcur[rl], 1);
        unsigned vbf = (unsigned short)f2bf(__int_as_float(e.y));
        epakB[p] = (e.x & 0xffff) | (vbf << 16);
    }
}

// ---------- fused 3-GEMM, single LDS slot (34.8KB -> 4 blocks/CU), 3 passes ----------
__global__ __launch_bounds__(256) void k_gemm3(const float* __restrict__ x,
                                               const short* __restrict__ wbf,  // thT|WtT|WhT
                                               const float* __restrict__ norm,
                                               const float* __restrict__ bt,
                                               short* __restrict__ Y,
                                               unsigned* __restrict__ outgh) {
    __shared__ short lb[HD * LDW];       // 34816 B -> 4 blocks/CU
    int tx = threadIdx.x;
    int wv = tx >> 6, l = tx & 63;
    long row0 = (long)blockIdx.x * 64 + wv * 16;
    int mrow = l & 15, kg = l >> 4;
    const float* xp = x + (row0 + mrow) * HD + kg * 8;

    short8 af[4];
    #pragma unroll
    for (int c = 0; c < 4; ++c) {
        float4 a0 = *(const float4*)(xp + c * 32);
        float4 a1 = *(const float4*)(xp + c * 32 + 4);
        short8 a;
        a[0]=f2bf(a0.x); a[1]=f2bf(a0.y); a[2]=f2bf(a0.z); a[3]=f2bf(a0.w);
        a[4]=f2bf(a1.x); a[5]=f2bf(a1.y); a[6]=f2bf(a1.z); a[7]=f2bf(a1.w);
        af[c] = a;
    }

    // ---- pass 1: theta ----
    for (int i = tx; i < HD * 16; i += 256) {
        int n = i >> 4, kc = (i & 15) << 3;
        *(float4*)(&lb[n * LDW + kc]) = *(const float4*)(&wbf[n * HD + kc]);
    }
    __syncthreads();
    f32x4 ac[8];
    #pragma unroll
    for (int f = 0; f < 8; ++f) ac[f] = (f32x4){0.f,0.f,0.f,0.f};
    #pragma unroll
    for (int c = 0; c < 4; ++c)
        #pragma unroll
        for (int f = 0; f < 8; ++f) {
            short8 b = *(short8*)(&lb[(16 * f + mrow) * LDW + c * 32 + kg * 8]);
            ac[f] = __builtin_amdgcn_mfma_f32_16x16x32_bf16(af[c], b, ac[f], 0, 0, 0);
        }
    float nr[4];
    #pragma unroll
    for (int r = 0; r < 4; ++r) nr[r] = norm[row0 + kg * 4 + r];
    #pragma unroll
    for (int f = 0; f < 8; ++f)
        #pragma unroll
        for (int r = 0; r < 4; ++r)
            Y[(row0 + kg * 4 + r) * HD + 16 * f + mrow] = f2bf(ac[f][r] * nr[r]);

    // ---- pass 2: W_t -> gate ----
    __syncthreads();
    for (int i = tx; i < HD * 16; i += 256) {
        int n = i >> 4, kc = (i & 15) << 3;
        *(float4*)(&lb[n * LDW + kc]) = *(const float4*)(&wbf[16384 + n * HD + kc]);
    }
    __syncthreads();
    #pragma unroll
    for (int f = 0; f < 8; ++f) ac[f] = (f32x4){0.f,0.f,0.f,0.f};
    #pragma unroll
    for (int c = 0; c < 4; ++c)
        #pragma unroll
        for (int f = 0; f < 8; ++f) {
            short8 b = *(short8*)(&lb[(16 * f + mrow) * LDW + c * 32 + kg * 8]);
            ac[f] = __builtin_amdgcn_mfma_f32_16x16x32_bf16(af[c], b, ac[f], 0, 0, 0);
        }
    unsigned g16[16];
    #pragma unroll
    for (int f = 0; f < 8; ++f) {
        float bb = bt[16 * f + mrow];
        #pragma unroll
        for (int r = 0; r < 4; ++r) {
            int q = f * 4 + r;
            float g = 1.f / (1.f + __expf(-(ac[f][r] + bb)));
            unsigned gb = (unsigned short)f2bf(g);
            if (q & 1) g16[q >> 1] |= gb << 16;
            else       g16[q >> 1]  = gb;
        }
    }

    // ---- pass 3: W_h -> het; pack gate|het into out ----
    __syncthreads();
    for (int i = tx; i < HD * 16; i += 256) {
        int n = i >> 4, kc = (i & 15) << 3;
        *(float4*)(&lb[n * LDW + kc]) = *(const float4*)(&wbf[2 * 16384 + n * HD + kc]);
    }
    __syncthreads();
    #pragma unroll
    for (int f = 0; f < 8; ++f) ac[f] = (f32x4){0.f,0.f,0.f,0.f};
    #pragma unroll
    for (int c = 0; c < 4; ++c)
        #pragma unroll
        for (int f = 0; f < 8; ++f) {
            short8 b = *(short8*)(&lb[(16 * f + mrow) * LDW + c * 32 + kg * 8]);
            ac[f] = __builtin_amdgcn_mfma_f32_16x16x32_bf16(af[c], b, ac[f], 0, 0, 0);
        }
    #pragma unroll
    for (int f = 0; f < 8; ++f)
        #pragma unroll
        for (int r = 0; r < 4; ++r) {
            int q = f * 4 + r;
            long idx = (row0 + kg * 4 + r) * HD + 16 * f + mrow;
            unsigned gb = (q & 1) ? (g16[q >> 1] >> 16) : (g16[q >> 1] & 0xffffu);
            unsigned hhi = (unsigned short)f2bf(ac[f][r]);
            outgh[idx] = gb | (hhi << 16);
        }
}

// ---------- gather SpMM + gating epilogue; 2 rows/wave (prologue amortized) ----------
__global__ __launch_bounds__(256) void k_gather(const int* __restrict__ rowptr,
                                                const int* __restrict__ total,
                                                const int* __restrict__ epak,
                                                const short* __restrict__ Y,
                                                const float* __restrict__ norm,
                                                float* __restrict__ out) {
    int batch = blockIdx.x & 7;
    int ib    = blockIdx.x >> 3;
    int wave = threadIdx.x >> 6, lane = threadIdx.x & 63;
    long r0 = (long)batch * NNODE + ib * 8 + wave * 2;
    long r1 = r0 + 1;
    // dual prologue: all loads for BOTH rows issued before any edge work
    uint2 gh0 = ((const uint2*)(out + r0 * HD))[lane];
    uint2 gh1 = ((const uint2*)(out + r1 * HD))[lane];
    float nrm0 = norm[r0], nrm1 = norm[r1];
    int p0a = __builtin_amdgcn_readfirstlane(rowptr[r0]);
    int n0e = __builtin_amdgcn_readfirstlane(total[r0]);
    int p1a = __builtin_amdgcn_readfirstlane(rowptr[r1]);
    int n1e = __builtin_amdgcn_readfirstlane(total[r1]);
    const char* Yb = (const char*)Y + (size_t)batch * NNODE * HD * 2;  // scalar base
    unsigned lo4 = (unsigned)lane * 4;

    auto row_sum = [&](int p0, int n, float& ax, float& ay) {
        const int* ep = epak + p0;
        int i = 0;
        for (; i + 16 <= n; i += 16) {
            int4 mA = *(const int4*)(ep + i);
            int4 mB = *(const int4*)(ep + i + 4);
            int4 mC = *(const int4*)(ep + i + 8);
            int4 mD = *(const int4*)(ep + i + 12);
            unsigned y0 = *(const unsigned*)(Yb + (((unsigned)mA.x & 0xffffu) << 8) + lo4);
            unsigned y1 = *(const unsigned*)(Yb + (((unsigned)mA.y & 0xffffu) << 8) + lo4);
            unsigned y2 = *(const unsigned*)(Yb + (((unsigned)mA.z & 0xffffu) << 8) + lo4);
            unsigned y3 = *(const unsigned*)(Yb + (((unsigned)mA.w & 0xffffu) << 8) + lo4);
            unsigned y4 = *(const unsigned*)(Yb + (((unsigned)mB.x & 0xffffu) << 8) + lo4);
            unsigned y5 = *(const unsigned*)(Yb + (((unsigned)mB.y & 0xffffu) << 8) + lo4);
            unsigned y6 = *(const unsigned*)(Yb + (((unsigned)mB.z & 0xffffu) << 8) + lo4);
            unsigned y7 = *(const unsigned*)(Yb + (((unsigned)mB.w & 0xffffu) << 8) + lo4);
            unsigned y8 = *(const unsigned*)(Yb + (((unsigned)mC.x & 0xffffu) << 8) + lo4);
            unsigned y9 = *(const unsigned*)(Yb + (((unsigned)mC.y & 0xffffu) << 8) + lo4);
            unsigned yA = *(const unsigned*)(Yb + (((unsigned)mC.z & 0xffffu) << 8) + lo4);
            unsigned yB = *(const unsigned*)(Yb + (((unsigned)mC.w & 0xffffu) << 8) + lo4);
            unsigned yC = *(const unsigned*)(Yb + (((unsigned)mD.x & 0xffffu) << 8) + lo4);
            unsigned yD = *(const unsigned*)(Yb + (((unsigned)mD.y & 0xffffu) << 8) + lo4);
            unsigned yE = *(const unsigned*)(Yb + (((unsigned)mD.z & 0xffffu) << 8) + lo4);
            unsigned yF = *(const unsigned*)(Yb + (((unsigned)mD.w & 0xffffu) << 8) + lo4);
            float v0 = bfhi((unsigned)mA.x), v1 = bfhi((unsigned)mA.y);
            float v2 = bfhi((unsigned)mA.z), v3 = bfhi((unsigned)mA.w);
            float v4 = bfhi((unsigned)mB.x), v5 = bfhi((unsigned)mB.y);
            float v6 = bfhi((unsigned)mB.z), v7 = bfhi((unsigned)mB.w);
            float v8 = bfhi((unsigned)mC.x), v9 = bfhi((unsigned)mC.y);
            float vA = bfhi((unsigned)mC.z), vB = bfhi((unsigned)mC.w);
            float vC = bfhi((unsigned)mD.x), vD = bfhi((unsigned)mD.y);
            float vE = bfhi((unsigned)mD.z), vF = bfhi((unsigned)mD.w);
            ax += v0 * bflo(y0); ay += v0 * bfhi(y0);
            ax += v1 * bflo(y1); ay += v1 * bfhi(y1);
            ax += v2 * bflo(y2); ay += v2 * bfhi(y2);
            ax += v3 * bflo(y3); ay += v3 * bfhi(y3);
            ax += v4 * bflo(y4); ay += v4 * bfhi(y4);
            ax += v5 * bflo(y5); ay += v5 * bfhi(y5);
            ax += v6 * bflo(y6); ay += v6 * bfhi(y6);
            ax += v7 * bflo(y7); ay += v7 * bfhi(y7);
            ax += v8 * bflo(y8); ay += v8 * bfhi(y8);
            ax += v9 * bflo(y9); ay += v9 * bfhi(y9);
            ax += vA * bflo(yA); ay += vA * bfhi(yA);
            ax += vB * bflo(yB); ay += vB * bfhi(yB);
            ax += vC * bflo(yC); ay += vC * bfhi(yC);
            ax += vD * bflo(yD); ay += vD * bfhi(yD);
            ax += vE * bflo(yE); ay += vE * bfhi(yE);
            ax += vF * bflo(yF); ay += vF * bfhi(yF);
        }
        for (; i + 4 <= n; i += 4) {
            int4 mA = *(const int4*)(ep + i);
            unsigned y0 = *(const unsigned*)(Yb + (((unsigned)mA.x & 0xffffu) << 8) + lo4);
            unsigned y1 = *(const unsigned*)(Yb + (((unsigned)mA.y & 0xffffu) << 8) + lo4);
            unsigned y2 = *(const unsigned*)(Yb + (((unsigned)mA.z & 0xffffu) << 8) + lo4);
            unsigned y3 = *(const unsigned*)(Yb + (((unsigned)mA.w & 0xffffu) << 8) + lo4);
            float v0 = bfhi((unsigned)mA.x), v1 = bfhi((unsigned)mA.y);
            float v2 = bfhi((unsigned)mA.z), v3 = bfhi((unsigned)mA.w);
            ax += v0 * bflo(y0); ay += v0 * bfhi(y0);
            ax += v1 * bflo(y1); ay += v1 * bfhi(y1);
            ax += v2 * bflo(y2); ay += v2 * bfhi(y2);
            ax += v3 * bflo(y3); ay += v3 * bfhi(y3);
        }
        for (; i < n; ++i) {
            unsigned e = (unsigned)ep[i];
            unsigned y = *(const unsigned*)(Yb + ((e & 0xffffu) << 8) + lo4);
            float v = bfhi(e);
            ax += v * bflo(y); ay += v * bfhi(y);
        }
    };

    float ax0 = 0.f, ay0 = 0.f, ax1 = 0.f, ay1 = 0.f;
    row_sum(p0a, n0e, ax0, ay0);
    row_sum(p1a, n1e, ax1, ay1);

    {
        float g0 = bflo(gh0.x), h0 = bfhi(gh0.x);
        float g1 = bflo(gh0.y), h1 = bfhi(gh0.y);
        float z0 = ax0 * nrm0, z1 = ay0 * nrm0;
        ((float2*)(out + r0 * HD))[lane] =
            make_float2(g0 * z0 + (1.f - g0) * h0, g1 * z1 + (1.f - g1) * h1);
    }
    {
        float g0 = bflo(gh1.x), h0 = bfhi(gh1.x);
        float g1 = bflo(gh1.y), h1 = bfhi(gh1.y);
        float z0 = ax1 * nrm1, z1 = ay1 * nrm1;
        ((float2*)(out + r1 * HD))[lane] =
            make_float2(g0 * z0 + (1.f - g0) * h0, g1 * z1 + (1.f - g1) * h1);
    }
}

extern "C" void kernel_launch(void* const* d_in, const int* in_sizes, int n_in,
                              void* d_out, int out_size, void* d_ws, size_t ws_size,
                              hipStream_t stream) {
    const float* x     = (const float*)d_in[0];
    const float* adj   = (const float*)d_in[1];
    const int*   src   = (const int*)d_in[2];
    const int*   dst   = (const int*)d_in[3];
    const float* Wt    = (const float*)d_in[4];
    const float* bt    = (const float*)d_in[5];
    const float* Wh    = (const float*)d_in[6];
    const float* theta = (const float*)d_in[7];
    float* out = (float*)d_out;

    // workspace ~33.5 MB
    char* p = (char*)d_ws;
    float* norm   = (float*)p;  p += (size_t)NROW * 4;              // 320,000
    int*   total  = (int*)p;    p += (size_t)NROW * 4;              // 320,000
    int*   rowptr = (int*)p;    p += (size_t)NROW * 4;              // 320,000
    int*   tot_c  = (int*)p;    p += (size_t)NBT * 4;               // 5,120
    int*   cbaseA = (int*)p;    p += (size_t)NBT * 4;               // 5,120
    int*   cbaseB = (int*)p;    p += (size_t)NBT * 4;               // 5,120
    int*   cc     = (int*)p;    p += (size_t)BATCH * KB * NBP * 4;  // 327,680
    short* wbf    = (short*)p;  p += 3 * 16384 * 2;                 // 98,304
    // RegionA (20.48 MB): epairA (20.48M) -> Y (20.48M, after refine)
    int2*  epairA = (int2*)p;
    short* Y      = (short*)p;  p += (size_t)NROW * HD * 2;         // 20,480,000
    // RegionB: packed 4B edges, 4-padded rows
    int*   epakB  = (int*)p;    p += (size_t)(NEDG_TOT + NBT * 256) * 4; // 11,551,232

    k_hist  <<<BATCH * KB, 512, 0, stream>>>(src, cc);
    k_wsum  <<<WCVT_B + NBT / 256, 256, 0, stream>>>(theta, Wt, Wh, wbf, cc, tot_c);
    k_scanc <<<1, 256, 0, stream>>>(tot_c, cbaseA, cbaseB);
    k_boffc <<<NBT / 256, 256, 0, stream>>>(cbaseA, cc);
    k_scatA <<<BATCH * KB, 512, 0, stream>>>(adj, src, dst, cc, epairA);
    k_refine<<<BATCH * NBUCK, 256, 0, stream>>>(cbaseA, cbaseB, tot_c, epairA,
                                                rowptr, total, norm, epakB);
    k_gemm3 <<<NROW / 64, 256, 0, stream>>>(x, wbf, norm, bt, Y, (unsigned*)out); // Y over dead epairA
    k_gather<<<NROW / 8, 256, 0, stream>>>(rowptr, total, epakB, Y, norm, out);
}